// Round 11
// baseline (322.524 us; speedup 1.0000x reference)
//
#include <hip/hip_runtime.h>

constexpr int BATCH = 2048;
constexpr int NHID  = 512;
constexpr int H0    = 256;
constexpr int H1    = 256;
constexpr int SMAX  = 32;          // samples per tile (P(n>32) ~ 1e-11)
constexpr int KC    = 32;          // K-chunk rows (one MFMA K)
constexpr int NKC   = NHID / KC;   // 16 chunks

typedef __attribute__((ext_vector_type(8))) short short8v;  // bf16x8 frag
typedef __attribute__((ext_vector_type(4))) float f32x4;    // MFMA acc

static __device__ __forceinline__ unsigned short bf_hi(float f) {
    return (unsigned short)(__float_as_uint(f) >> 16);       // truncate to bf16
}
static __device__ __forceinline__ float bf_f(unsigned short h) {
    return __uint_as_float(((unsigned int)h) << 16);
}

// One block per parent p (grid = 256 = #CUs), 512 thr = 8 waves.
// GEMM per tile: [32 samples x 512] x [512 x 512(bot256|top256)] via
// mfma_f32_16x16x32_bf16, 3-term split (xh*wh + xl*wh + xh*wl; dropped
// xl*wl ~ 2^-16 rel -> ~1e-6 abs on outputs).
// Wave g: row-tile r=g&1 (rows 16r..16r+15), col-tiles ctb=(g>>1)*8..+8.
// gfx950 16x16x32 layouts: A: m=l&15, k=(l>>4)*8+e; B: n=l&15, k=(l>>4)*8+e;
// D: col=l&15, row=(l>>4)*4+j (m89-verified).
__global__ __launch_bounds__(512) void hs_mfma(
    const float* __restrict__ x,        // [B, NHID]
    const int*   __restrict__ labels,   // [B]
    const int*   __restrict__ parents,  // [B]
    const float* __restrict__ topW,     // [NHID, H0]
    const float* __restrict__ topb,     // [H0]
    const float* __restrict__ botW,     // [H0, NHID, H1]
    const float* __restrict__ botb,     // [H0, H1]
    float*       __restrict__ out)      // [B]
{
    const int p = blockIdx.x;
    const int t = threadIdx.x;         // 0..511
    const int g = t >> 6;              // wave 0..7
    const int l = t & 63;

    __shared__ int list[BATCH];                                // 8 KB
    __shared__ int wcnt[8];
    __shared__ __align__(16) unsigned short Ahi[SMAX * NHID];  // 32 KB (swz)
    __shared__ __align__(16) unsigned short Alo[SMAX * NHID];  // 32 KB (swz)
    __shared__ __align__(16) float Bf[KC * NHID];              // 64 KB (swz)

    // ---- deterministic list build (r1/r9-verified 512-thr ballot scan)
    int running = 0;
    for (int c = 0; c < BATCH; c += 512) {
        const bool match = (parents[c + t] == p);
        const unsigned long long mask = __ballot(match);
        if (l == 0) wcnt[g] = __popcll(mask);
        __syncthreads();
        int off = running;
        #pragma unroll
        for (int w = 0; w < 8; ++w) {
            const int cw = wcnt[w];
            if (w < g) off += cw;
            running += cw;
        }
        if (match)
            list[off + __popcll(mask & ((1ull << l) - 1ull))] = c + t;
        __syncthreads();
    }
    const int n = running;
    if (n == 0) return;    // block-uniform exit

    const float4 bb = *(const float4*)(botb + (size_t)p * H1 + 4 * l);
    const float4 bt = *(const float4*)(topb + 4 * l);

    const int r   = g & 1;          // row-tile
    const int ctb = (g >> 1) * 8;   // col-tile base (8 tiles = 128 cols)
    const int sk  = t >> 4;         // staging: chunk-local k row (0..31)
    const int sc  = 4 * (t & 15);   // staging: col phase
    const float* bW = botW + (size_t)p * NHID * H1;

    for (int base = 0; base < n; base += SMAX) {    // ~always exactly 1 tile
        const int rem = min(SMAX, n - base);

        // ---- A: stage x rows, bf16 hi/lo, XOR row-swizzle
        {
            const int s  = t >> 4;               // 0..31
            const int c0 = 32 * (t & 15);        // 32 cols per thread
            const float* xr =
                x + (size_t)list[base + min(s, rem - 1)] * NHID + c0;
            #pragma unroll
            for (int b = 0; b < 4; ++b) {
                const float4 v0 = ((const float4*)xr)[2 * b];
                const float4 v1 = ((const float4*)xr)[2 * b + 1];
                const float fe[8] = {v0.x, v0.y, v0.z, v0.w,
                                     v1.x, v1.y, v1.z, v1.w};
                short8v hv, lv;
                #pragma unroll
                for (int e = 0; e < 8; ++e) {
                    const unsigned short h = bf_hi(fe[e]);
                    hv[e] = (short)h;
                    lv[e] = (short)bf_hi(fe[e] - bf_f(h));
                }
                const int byte = ((s * NHID + c0 + 8 * b) * 2) ^ ((s & 7) << 4);
                *(short8v*)((char*)Ahi + byte) = hv;
                *(short8v*)((char*)Alo + byte) = lv;
            }
        }

        f32x4 acc[8];
        #pragma unroll
        for (int i = 0; i < 8; ++i) acc[i] = (f32x4)(0.0f);

        float4 sreg[8];
        __syncthreads();                 // A visible; prev logits consumed

        // issue W chunk 0 (bot slice cols 0..255 | top cols 0..255)
        {
            const float* bsrc = bW + (size_t)sk * H1 + sc;
            const float* tsrc = topW + (size_t)sk * H0 + sc;
            #pragma unroll
            for (int i = 0; i < 4; ++i) {
                sreg[i]     = *(const float4*)(bsrc + 64 * i);
                sreg[4 + i] = *(const float4*)(tsrc + 64 * i);
            }
        }

        for (int kc = 0; kc < NKC; ++kc) {
            __syncthreads();             // Bf free (chunk kc-1 fully consumed)
            #pragma unroll
            for (int i = 0; i < 8; ++i) {    // write staged chunk (k-swizzle)
                const int c    = sc + 64 * i;
                const int byte = ((sk * NHID + c) * 4) ^ ((sk & 7) << 4);
                *(float4*)((char*)Bf + byte) = sreg[i];
            }
            __syncthreads();             // Bf ready

            if (kc + 1 < NKC) {          // T14: next chunk flies under compute
                const int k0 = (kc + 1) * KC + sk;
                const float* bsrc = bW + (size_t)k0 * H1 + sc;
                const float* tsrc = topW + (size_t)k0 * H0 + sc;
                #pragma unroll
                for (int i = 0; i < 4; ++i) {
                    sreg[i]     = *(const float4*)(bsrc + 64 * i);
                    sreg[4 + i] = *(const float4*)(tsrc + 64 * i);
                }
            }

            // ---- compute chunk kc
            const int K0   = kc * KC;
            const int arow = 16 * r + (l & 15);
            const int ab   = ((arow * NHID + K0 + (l >> 4) * 8) * 2)
                             ^ ((arow & 7) << 4);
            const short8v af_h = *(const short8v*)((const char*)Ahi + ab);
            const short8v af_l = *(const short8v*)((const char*)Alo + ab);

            #pragma unroll
            for (int i = 0; i < 8; ++i) {
                const int cB = 16 * (ctb + i) + (l & 15);
                float bfv[8];
                #pragma unroll
                for (int e = 0; e < 8; ++e) {
                    const int kk   = (l >> 4) * 8 + e;
                    const int byte = ((kk * NHID + cB) * 4) ^ ((kk & 7) << 4);
                    bfv[e] = *(const float*)((const char*)Bf + byte);
                }
                short8v bh, bl;
                #pragma unroll
                for (int e = 0; e < 8; ++e) {
                    const unsigned short h = bf_hi(bfv[e]);
                    bh[e] = (short)h;
                    bl[e] = (short)bf_hi(bfv[e] - bf_f(h));
                }
                acc[i] = __builtin_amdgcn_mfma_f32_16x16x32_bf16(
                             af_h, bh, acc[i], 0, 0, 0);
                acc[i] = __builtin_amdgcn_mfma_f32_16x16x32_bf16(
                             af_l, bh, acc[i], 0, 0, 0);
                acc[i] = __builtin_amdgcn_mfma_f32_16x16x32_bf16(
                             af_h, bl, acc[i], 0, 0, 0);
            }
        }

        __syncthreads();                 // all waves done reading Bf
        // ---- acc -> logits (plain [32][512] overlay on Bf)
        #pragma unroll
        for (int i = 0; i < 8; ++i) {
            const int col = 16 * (ctb + i) + (l & 15);
            #pragma unroll
            for (int j = 0; j < 4; ++j) {
                const int row = 16 * r + (l >> 4) * 4 + j;
                Bf[row * NHID + col] = acc[i][j];
            }
        }
        __syncthreads();                 // logits complete

        // ---- two softmaxes per sample; wave g owns samples 4g..4g+3
        #pragma unroll
        for (int i = 0; i < 4; ++i) {
            const int s = 4 * g + i;
            if (s < rem) {               // wave-uniform (s, rem uniform/wave)
                const int idx = list[base + s];
                const float* Lrow = Bf + s * NHID;

                // bottom softmax (cols 0..255), target labels[idx]
                float4 v = *(const float4*)(Lrow + 4 * l);
                v.x += bb.x; v.y += bb.y; v.z += bb.z; v.w += bb.w;
                float m = fmaxf(fmaxf(v.x, v.y), fmaxf(v.z, v.w));
                #pragma unroll
                for (int off = 32; off > 0; off >>= 1)
                    m = fmaxf(m, __shfl_xor(m, off, 64));
                const float ex = expf(v.x - m), ey = expf(v.y - m);
                const float ez = expf(v.z - m), ew = expf(v.w - m);
                float sum = (ex + ey) + (ez + ew);
                #pragma unroll
                for (int off = 32; off > 0; off >>= 1)
                    sum += __shfl_xor(sum, off, 64);
                const int tb_ = labels[idx];
                const int kb_ = tb_ & 3;
                const float evb = (kb_ == 0) ? ex : (kb_ == 1) ? ey
                                : (kb_ == 2) ? ez : ew;
                const float pb = __shfl(evb / sum, tb_ >> 2, 64);

                // top softmax (cols 256..511), target p
                float4 u = *(const float4*)(Lrow + 256 + 4 * l);
                u.x += bt.x; u.y += bt.y; u.z += bt.z; u.w += bt.w;
                float mu = fmaxf(fmaxf(u.x, u.y), fmaxf(u.z, u.w));
                #pragma unroll
                for (int off = 32; off > 0; off >>= 1)
                    mu = fmaxf(mu, __shfl_xor(mu, off, 64));
                const float tx = expf(u.x - mu), ty = expf(u.y - mu);
                const float tz = expf(u.z - mu), tw = expf(u.w - mu);
                float tsum = (tx + ty) + (tz + tw);
                #pragma unroll
                for (int off = 32; off > 0; off >>= 1)
                    tsum += __shfl_xor(tsum, off, 64);
                const int kt_ = p & 3;
                const float evt = (kt_ == 0) ? tx : (kt_ == 1) ? ty
                                : (kt_ == 2) ? tz : tw;
                const float pt = __shfl(evt / tsum, p >> 2, 64);

                if (l == 0) out[idx] = pt * pb;
            }
        }
        __syncthreads();                 // Bf (logits) reusable next tile
    }
}

extern "C" void kernel_launch(void* const* d_in, const int* in_sizes, int n_in,
                              void* d_out, int out_size, void* d_ws, size_t ws_size,
                              hipStream_t stream) {
    const float* x       = (const float*)d_in[0];
    const int*   labels  = (const int*)  d_in[1];
    const int*   parents = (const int*)  d_in[2];
    const float* topW    = (const float*)d_in[3];
    const float* topb    = (const float*)d_in[4];
    const float* botW    = (const float*)d_in[5];
    const float* botb    = (const float*)d_in[6];
    float*       out     = (float*)d_out;

    hs_mfma<<<H0, 512, 0, stream>>>(x, labels, parents,
                                    topW, topb, botW, botb, out);
}

// Round 12
// 216.815 us; speedup vs baseline: 1.4876x; 1.4876x over previous
//
#include <hip/hip_runtime.h>

constexpr int BATCH = 2048;
constexpr int NHID  = 512;
constexpr int H0    = 256;
constexpr int H1    = 256;
constexpr int SMAX  = 32;          // samples per tile (P(n>32) ~ 1e-11)
constexpr int NKC   = 16;          // K chunks of 32

typedef __attribute__((ext_vector_type(8))) short short8v;  // bf16x8 frag
typedef __attribute__((ext_vector_type(4))) float f32x4;    // MFMA acc

static __device__ __forceinline__ unsigned short bf_hi(float f) {
    return (unsigned short)(__float_as_uint(f) >> 16);       // truncate
}
static __device__ __forceinline__ float bf_f(unsigned short h) {
    return __uint_as_float(((unsigned int)h) << 16);
}

// One block per parent p (grid = 256 = #CUs), 1024 thr = 16 waves (4/SIMD).
// Logits L[32][512] = X[32x512] * [botW[p] | topW] via mfma_f32_16x16x32_bf16,
// 3-term hi/lo split (r11-verified numerics, absmax 4.8e-7).
// B path: waves load W fragments DIRECTLY global->reg (fully coalesced:
// per instr 4x64B runs, tile-pairing fills 128B lines), convert in-reg,
// pipeline 1 chunk ahead. No B LDS, no staging regs held across MFMA
// (r11's 247MB spill), no scalar LDS reads (r11's 5M bank conflicts).
// A in LDS: r11-verified layout/swizzle/reads. No barriers in the K loop.
// Wave g<8: bottom cols 32g..+31 (tiles 2g,2g+1); g>=8: top ditto.
__global__ __launch_bounds__(1024) void hs_mfma2(
    const float* __restrict__ x,        // [B, NHID]
    const int*   __restrict__ labels,   // [B]
    const int*   __restrict__ parents,  // [B]
    const float* __restrict__ topW,     // [NHID, H0]
    const float* __restrict__ topb,     // [H0]
    const float* __restrict__ botW,     // [H0, NHID, H1]
    const float* __restrict__ botb,     // [H0, H1]
    float*       __restrict__ out)      // [B]
{
    const int p  = blockIdx.x;
    const int t  = threadIdx.x;        // 0..1023
    const int g  = t >> 6;             // wave 0..15
    const int l  = t & 63;
    const int lh = l >> 4;             // 0..3
    const int li = l & 15;

    __shared__ int list[BATCH];                 // 8 KB
    __shared__ int wcnt[16];
    // A hi (32KB) + A lo (32KB) + 16KB pad (forces 1 block/CU -> 4 w/SIMD
    // -> 128-VGPR cap, we need ~95). Logits [32][512] f32 overlay after K.
    __shared__ __align__(16) char AL[81920];
    float* Lg = (float*)AL;

    // ---- deterministic list build (verified ballot scan, 16-wave form)
    int running = 0;
    for (int c = 0; c < BATCH; c += 1024) {
        const bool match = (parents[c + t] == p);
        const unsigned long long mask = __ballot(match);
        if (l == 0) wcnt[g] = __popcll(mask);
        __syncthreads();
        int off = running;
        #pragma unroll
        for (int w = 0; w < 16; ++w) {
            const int cw = wcnt[w];
            if (w < g) off += cw;
            running += cw;
        }
        if (match)
            list[off + __popcll(mask & ((1ull << l) - 1ull))] = c + t;
        __syncthreads();
    }
    const int n = running;
    if (n == 0) return;    // block-uniform exit

    const float4 bb = *(const float4*)(botb + (size_t)p * H1 + 4 * l);
    const float4 bt = *(const float4*)(topb + 4 * l);

    const bool bot = (g < 8);
    const int  wv  = g & 7;
    const float* Wsrc = bot ? botW + (size_t)p * NHID * H1 : topW;
    const int colL = 32 * wv + li;     // lane col (tile tt adds 16*tt)

    for (int base = 0; base < n; base += SMAX) {    // ~always 1 iteration
        const int rem = min(SMAX, n - base);

        // ---- A stage (threads 0..511; r11-verified layout & swizzle)
        if (t < 512) {
            const int s  = t >> 4;
            const int c0 = 32 * (t & 15);
            const float* xr =
                x + (size_t)list[base + min(s, rem - 1)] * NHID + c0;
            #pragma unroll
            for (int b = 0; b < 4; ++b) {
                const float4 v0 = ((const float4*)xr)[2 * b];
                const float4 v1 = ((const float4*)xr)[2 * b + 1];
                const float fe[8] = {v0.x, v0.y, v0.z, v0.w,
                                     v1.x, v1.y, v1.z, v1.w};
                short8v hv, lv;
                #pragma unroll
                for (int e = 0; e < 8; ++e) {
                    const unsigned short h = bf_hi(fe[e]);
                    hv[e] = (short)h;
                    lv[e] = (short)bf_hi(fe[e] - bf_f(h));
                }
                const int byte = ((s * NHID + c0 + 8 * b) * 2) ^ ((s & 7) << 4);
                *(short8v*)(AL + byte)         = hv;   // A hi
                *(short8v*)(AL + 32768 + byte) = lv;   // A lo
            }
        }
        __syncthreads();   // A visible to all waves

        f32x4 acc[2][2];   // [tt][r], static indices only
        #pragma unroll
        for (int tt = 0; tt < 2; ++tt)
            #pragma unroll
            for (int r = 0; r < 2; ++r) acc[tt][r] = (f32x4)(0.0f);

        // ---- pipeline prologue: chunk 0 W fragments -> regs
        float bx0[8], bx1[8];
        #pragma unroll
        for (int e = 0; e < 8; ++e) {
            const size_t rowb = (size_t)(8 * lh + e) * 256;
            bx0[e] = Wsrc[rowb + colL];
            bx1[e] = Wsrc[rowb + colL + 16];
        }

        for (int kc = 0; kc < NKC; ++kc) {
            // convert this chunk's B to bf16 hi/lo frags (frees bx for next)
            short8v bh0, bl0, bh1, bl1;
            #pragma unroll
            for (int e = 0; e < 8; ++e) {
                const unsigned short h0 = bf_hi(bx0[e]);
                bh0[e] = (short)h0;
                bl0[e] = (short)bf_hi(bx0[e] - bf_f(h0));
                const unsigned short h1 = bf_hi(bx1[e]);
                bh1[e] = (short)h1;
                bl1[e] = (short)bf_hi(bx1[e] - bf_f(h1));
            }
            // issue next chunk's loads (fly under MFMA + A reads)
            if (kc + 1 < NKC) {
                #pragma unroll
                for (int e = 0; e < 8; ++e) {
                    const size_t rowb =
                        (size_t)((kc + 1) * 32 + 8 * lh + e) * 256;
                    bx0[e] = Wsrc[rowb + colL];
                    bx1[e] = Wsrc[rowb + colL + 16];
                }
            }
            // A fragments for this chunk (r11-verified read path)
            const int K0 = kc * 32;
            short8v afh[2], afl[2];
            #pragma unroll
            for (int r = 0; r < 2; ++r) {
                const int arow = 16 * r + li;
                const int ab   = ((arow * NHID + K0 + lh * 8) * 2)
                                 ^ ((arow & 7) << 4);
                afh[r] = *(const short8v*)(AL + ab);
                afl[r] = *(const short8v*)(AL + 32768 + ab);
            }
            // 12 MFMA: 2 col-tiles x 2 row-tiles x 3 terms
            #pragma unroll
            for (int r = 0; r < 2; ++r) {
                acc[0][r] = __builtin_amdgcn_mfma_f32_16x16x32_bf16(
                                afh[r], bh0, acc[0][r], 0, 0, 0);
                acc[0][r] = __builtin_amdgcn_mfma_f32_16x16x32_bf16(
                                afl[r], bh0, acc[0][r], 0, 0, 0);
                acc[0][r] = __builtin_amdgcn_mfma_f32_16x16x32_bf16(
                                afh[r], bl0, acc[0][r], 0, 0, 0);
                acc[1][r] = __builtin_amdgcn_mfma_f32_16x16x32_bf16(
                                afh[r], bh1, acc[1][r], 0, 0, 0);
                acc[1][r] = __builtin_amdgcn_mfma_f32_16x16x32_bf16(
                                afl[r], bh1, acc[1][r], 0, 0, 0);
                acc[1][r] = __builtin_amdgcn_mfma_f32_16x16x32_bf16(
                                afh[r], bl1, acc[1][r], 0, 0, 0);
            }
        }
        __syncthreads();   // all A reads done -> AL reusable as logits

        // ---- D -> logits (r11-verified mapping: col=li, row=lh*4+j)
        const int cg = (bot ? 0 : 256) + 32 * wv;
        #pragma unroll
        for (int tt = 0; tt < 2; ++tt) {
            #pragma unroll
            for (int r = 0; r < 2; ++r) {
                #pragma unroll
                for (int j = 0; j < 4; ++j) {
                    const int row = 16 * r + lh * 4 + j;
                    Lg[row * NHID + cg + 16 * tt + li] = acc[tt][r][j];
                }
            }
        }
        __syncthreads();   // logits complete

        // ---- two softmaxes per sample (r11-verified); waves 0-7 only
        if (g < 8) {
            #pragma unroll
            for (int i2 = 0; i2 < 4; ++i2) {
                const int s = 4 * g + i2;
                if (s < rem) {               // wave-uniform
                    const int idx = list[base + s];
                    const float* Lrow = Lg + s * NHID;

                    float4 v = *(const float4*)(Lrow + 4 * l);
                    v.x += bb.x; v.y += bb.y; v.z += bb.z; v.w += bb.w;
                    float m = fmaxf(fmaxf(v.x, v.y), fmaxf(v.z, v.w));
                    #pragma unroll
                    for (int off = 32; off > 0; off >>= 1)
                        m = fmaxf(m, __shfl_xor(m, off, 64));
                    const float ex = expf(v.x - m), ey = expf(v.y - m);
                    const float ez = expf(v.z - m), ew = expf(v.w - m);
                    float sum = (ex + ey) + (ez + ew);
                    #pragma unroll
                    for (int off = 32; off > 0; off >>= 1)
                        sum += __shfl_xor(sum, off, 64);
                    const int tb_ = labels[idx];
                    const int kb_ = tb_ & 3;
                    const float evb = (kb_ == 0) ? ex : (kb_ == 1) ? ey
                                    : (kb_ == 2) ? ez : ew;
                    const float pb = __shfl(evb / sum, tb_ >> 2, 64);

                    float4 u = *(const float4*)(Lrow + 256 + 4 * l);
                    u.x += bt.x; u.y += bt.y; u.z += bt.z; u.w += bt.w;
                    float mu = fmaxf(fmaxf(u.x, u.y), fmaxf(u.z, u.w));
                    #pragma unroll
                    for (int off = 32; off > 0; off >>= 1)
                        mu = fmaxf(mu, __shfl_xor(mu, off, 64));
                    const float tx = expf(u.x - mu), ty = expf(u.y - mu);
                    const float tz = expf(u.z - mu), tw = expf(u.w - mu);
                    float tsum = (tx + ty) + (tz + tw);
                    #pragma unroll
                    for (int off = 32; off > 0; off >>= 1)
                        tsum += __shfl_xor(tsum, off, 64);
                    const int kt_ = p & 3;
                    const float evt = (kt_ == 0) ? tx : (kt_ == 1) ? ty
                                    : (kt_ == 2) ? tz : tw;
                    const float pt = __shfl(evt / tsum, p >> 2, 64);

                    if (l == 0) out[idx] = pt * pb;
                }
            }
        }
        __syncthreads();   // AL reusable (A restage) next tile
    }
}

extern "C" void kernel_launch(void* const* d_in, const int* in_sizes, int n_in,
                              void* d_out, int out_size, void* d_ws, size_t ws_size,
                              hipStream_t stream) {
    const float* x       = (const float*)d_in[0];
    const int*   labels  = (const int*)  d_in[1];
    const int*   parents = (const int*)  d_in[2];
    const float* topW    = (const float*)d_in[3];
    const float* topb    = (const float*)d_in[4];
    const float* botW    = (const float*)d_in[5];
    const float* botb    = (const float*)d_in[6];
    float*       out     = (float*)d_out;

    hs_mfma2<<<H0, 1024, 0, stream>>>(x, labels, parents,
                                      topW, topb, botW, botb, out);
}